// Round 2
// baseline (1212.316 us; speedup 1.0000x reference)
//
#include <hip/hip_runtime.h>

// DecoderLSTM: 30-step LSTM, 8192 independent peds, H=256, E=64.
// R2: 64 peds/block (4 M-tiles), grid 128 -> weight stream halved.
//     B-fragment half-group double-buffered prefetch (4 frags in flight).
//     Phase A writes bf16 A-frags directly into h_stage (no fp32 h_lds).

typedef float  f32x4  __attribute__((ext_vector_type(4)));
typedef short  short8 __attribute__((ext_vector_type(8)));
typedef __bf16 bf16x8 __attribute__((ext_vector_type(8)));

#define WS_WHH_OFF 0
#define WS_WIH_OFF (512 * 1024)
#define WS_BIAS_OFF (640 * 1024)
#define WS_SCAL_OFF (640 * 1024 + 4096)

__device__ __forceinline__ unsigned short f2bf(float f) {
  unsigned int u = __float_as_uint(f);
  u += 0x7FFFu + ((u >> 16) & 1u);   // round-to-nearest-even
  return (unsigned short)(u >> 16);
}

__device__ __forceinline__ float sigm(float x) {
  return __builtin_amdgcn_rcpf(1.0f + __expf(-x));
}

__device__ __forceinline__ float tanh_(float x) {
  float ax = fabsf(x);
  float t = __expf(-2.0f * ax);
  float r = (1.0f - t) * __builtin_amdgcn_rcpf(1.0f + t);
  return x >= 0.0f ? r : -r;
}

__device__ __forceinline__ f32x4 mfma16(short8 a, short8 b, f32x4 c) {
  return __builtin_amdgcn_mfma_f32_16x16x32_bf16(
      __builtin_bit_cast(bf16x8, a), __builtin_bit_cast(bf16x8, b), c, 0, 0, 0);
}

// ---------------- Prologue 1: shuffle weights into B-frag-linear bf16 -------
// whh_s linear idx: (((w*8 + kc)*4 + g)*2 + nt2)*512 + l*8 + j
//   row = g*256 + w*32 + nt2*16 + (l&15), col = kc*32 + (l>>4)*8 + j
// wih_s: (((w*2 + kc2)*4 + g)*2 + nt2)*512 + l*8 + j  (col in [0,64))
extern "C" __global__ void shuffle_weights(const float* __restrict__ Wih,
                                           const float* __restrict__ Whh,
                                           unsigned short* __restrict__ whh_s,
                                           unsigned short* __restrict__ wih_s) {
  int t = blockIdx.x * 256 + threadIdx.x;
  if (t < 32768) {
    int l = t & 63; int x = t >> 6;
    int nt2 = x & 1; x >>= 1;
    int g = x & 3;  x >>= 2;
    int kc = x & 7; x >>= 3;
    int w = x;  // 0..7
    int row = g * 256 + w * 32 + nt2 * 16 + (l & 15);
    int col0 = kc * 32 + (l >> 4) * 8;
    const float* src = Whh + row * 256 + col0;
    unsigned short* dst = whh_s + t * 8;
#pragma unroll
    for (int j = 0; j < 8; j++) dst[j] = f2bf(src[j]);
  } else if (t < 40960) {
    int t2 = t - 32768;
    int l = t2 & 63; int x = t2 >> 6;
    int nt2 = x & 1; x >>= 1;
    int g = x & 3;   x >>= 2;
    int kc2 = x & 1; x >>= 1;
    int w = x;  // 0..7
    int row = g * 256 + w * 32 + nt2 * 16 + (l & 15);
    int col0 = kc2 * 32 + (l >> 4) * 8;
    const float* src = Wih + row * 64 + col0;
    unsigned short* dst = wih_s + t2 * 8;
#pragma unroll
    for (int j = 0; j < 8; j++) dst[j] = f2bf(src[j]);
  }
}

// ---------------- Prologue 2: bias = b_ih+b_hh; K/SP reductions -------------
extern "C" __global__ void prologue2(const float* __restrict__ b_ih,
                                     const float* __restrict__ b_hh,
                                     const float* __restrict__ ln2g,
                                     const float* __restrict__ ln2b,
                                     const float* __restrict__ posW,
                                     float* __restrict__ biasv,
                                     float* __restrict__ scal) {
  int t = threadIdx.x;  // 256 threads
#pragma unroll
  for (int k2 = 0; k2 < 4; k2++) {
    int n = t * 4 + k2;
    biasv[n] = b_ih[n] + b_hh[n];
  }
  __shared__ float red[256][4];
  float g = ln2g[t], b = ln2b[t], p0 = posW[t], p1 = posW[256 + t];
  red[t][0] = b * p0;
  red[t][1] = b * p1;
  red[t][2] = g * p0;
  red[t][3] = g * p1;
  __syncthreads();
  for (int s = 128; s > 0; s >>= 1) {
    if (t < s) {
#pragma unroll
      for (int v = 0; v < 4; v++) red[t][v] += red[t + s][v];
    }
    __syncthreads();
  }
  if (t == 0) {
#pragma unroll
    for (int v = 0; v < 4; v++) scal[v] = red[0][v];
  }
}

// ---------------- Main persistent decoder kernel ----------------------------
extern "C" __global__ __launch_bounds__(512, 2) void decoder_main(
    const float* __restrict__ lpr,   // last_pos_rel [8192][2]
    const float* __restrict__ h0,    // [8192][256]
    const float* __restrict__ c0,    // [8192][256]
    const float* __restrict__ embW,  // [64][2]
    const float* __restrict__ embB,  // [64]
    const float* __restrict__ ln1g, const float* __restrict__ ln1b,  // [2]
    const float* __restrict__ posW,  // [2][256]
    const float* __restrict__ posB,  // [2]
    const float* __restrict__ ln2g,  // [256]
    const unsigned short* __restrict__ whh_s,
    const unsigned short* __restrict__ wih_s,
    const float* __restrict__ biasv,  // [1024]
    const float* __restrict__ scal,   // [4] {K0,K1,SP0,SP1}
    float* __restrict__ out)          // [30][8192][2]
{
  // LDS (chunk stride 520 shorts = 1040 B: 16B-aligned, breaks bank aliasing)
  __shared__ unsigned short h_stage[32 * 520];  // (mt*8+kc) chunks, A-frag bf16
  __shared__ unsigned short x_stage[8 * 520];   // (mt*2+kc2) chunks
  __shared__ float partials[64 * 33];           // [ped][w*4+v]
  __shared__ float n01[64][2];                  // LN1'd rel per ped

  const int tid = threadIdx.x;
  const int w = tid >> 6;      // wave 0..7
  const int l = tid & 63;      // lane
  const int q = l >> 4;        // quad
  const int i = l & 15;
  const int P0 = blockIdx.x * 64;

  // staging map: 8 threads per ped
  const int pc = tid >> 3;     // ped 0..63
  const int s3 = tid & 7;

  const float K0 = scal[0], K1 = scal[1], SP0 = scal[2], SP1 = scal[3];
  const float pb0 = posB[0], pb1 = posB[1];
  const float g10 = ln1g[0], g11 = ln1g[1], b10 = ln1b[0], b11 = ln1b[1];

  float bias_r[4][2];
#pragma unroll
  for (int g = 0; g < 4; g++)
#pragma unroll
    for (int nt2 = 0; nt2 < 2; nt2++)
      bias_r[g][nt2] = biasv[g * 256 + w * 32 + nt2 * 16 + i];

  float Pp[2][2];  // [nt2][r]: ln2_g[u]*posW[r][u] at u = w*32+nt2*16+i
#pragma unroll
  for (int nt2 = 0; nt2 < 2; nt2++) {
    int u = w * 32 + nt2 * 16 + i;
    float gg = ln2g[u];
    Pp[nt2][0] = gg * posW[u];
    Pp[nt2][1] = gg * posW[256 + u];
  }

  // ---- c0 into C-layout registers (4 m-tiles) ----
  f32x4 c_r[4][2];
#pragma unroll
  for (int mt = 0; mt < 4; mt++)
#pragma unroll
    for (int nt2 = 0; nt2 < 2; nt2++)
#pragma unroll
      for (int r = 0; r < 4; r++)
        c_r[mt][nt2][r] =
            c0[(size_t)(P0 + mt * 16 + q * 4 + r) * 256 + w * 32 + nt2 * 16 + i];

  // ---- stage h0 (bf16 A-frag layout); thread = (pc, s3), kc = s3 ----
#pragma unroll
  for (int t2 = 0; t2 < 4; t2++) {
    float tf[8];
    const float* src = h0 + (size_t)(P0 + pc) * 256 + s3 * 32 + t2 * 8;
    *(float4*)&tf[0] = *(const float4*)(src);
    *(float4*)&tf[4] = *(const float4*)(src + 4);
    short8 sv;
#pragma unroll
    for (int j = 0; j < 8; j++) sv[j] = (short)f2bf(tf[j]);
    *(short8*)(h_stage + ((pc >> 4) * 8 + s3) * 520 + ((pc & 15) + 16 * t2) * 8) = sv;
  }

  // ---- initial n01 = LN1(last_pos_rel) ----
  if (tid < 64) {
    float r0 = lpr[(P0 + tid) * 2], r1 = lpr[(P0 + tid) * 2 + 1];
    float d = 0.5f * (r0 - r1);
    float rs = rsqrtf(d * d + 1e-5f);
    n01[tid][0] = d * rs * g10 + b10;
    n01[tid][1] = -d * rs * g11 + b11;
  }
  __syncthreads();

  // ---- initial x_stage = embed(n01); thread (pc, s3) handles k=s3*8..+8 ----
  {
    float n0 = n01[pc][0], n1 = n01[pc][1];
    short8 sv;
#pragma unroll
    for (int j = 0; j < 8; j++) {
      int k = s3 * 8 + j;
      float2 ew = ((const float2*)embW)[k];
      float e = n0 * ew.x + n1 * ew.y + embB[k];
      e = e > 0.f ? e : 0.01f * e;
      sv[j] = (short)f2bf(e);
    }
    *(short8*)(x_stage + ((pc >> 4) * 2 + (s3 >> 2)) * 520 +
               ((pc & 15) + 16 * (s3 & 3)) * 8) = sv;
  }

  const unsigned short* wihW = wih_s + w * (2 * 4 * 2 * 512);
  const unsigned short* whhW = whh_s + w * (8 * 4 * 2 * 512);
  const int loff = l * 8;

  __syncthreads();

  for (int st = 0; st < 30; st++) {
    // ---- acc init with bias ----
    f32x4 acc[4][4][2];  // [gate][mt][nt2]
#pragma unroll
    for (int g = 0; g < 4; g++)
#pragma unroll
      for (int mt = 0; mt < 4; mt++)
#pragma unroll
        for (int nt2 = 0; nt2 < 2; nt2++) {
          float bv = bias_r[g][nt2];
          acc[g][mt][nt2] = (f32x4){bv, bv, bv, bv};
        }

    // ---- pipelined GEMM: 10 kc-groups x 2 half-groups, B dbuf ----
    short8 bb[2][4];
    short8 a[4];
    {
      const unsigned short* gb = wihW;  // group 0 = wih kc2=0
#pragma unroll
      for (int jj = 0; jj < 4; jj++)
        bb[0][jj] = *(const short8*)(gb + jj * 512 + loff);
    }
#pragma unroll
    for (int hg = 0; hg < 20; hg++) {
      const int kc = hg >> 1, half = hg & 1, cur = hg & 1;
      if (hg < 19) {
        const int hn = hg + 1, kcn = hn >> 1, halfn = hn & 1;
        const unsigned short* gb =
            (kcn < 2) ? (wihW + kcn * 4096) : (whhW + (kcn - 2) * 4096);
#pragma unroll
        for (int jj = 0; jj < 4; jj++)
          bb[cur ^ 1][jj] = *(const short8*)(gb + (halfn * 4 + jj) * 512 + loff);
      }
      if (half == 0) {
        if (kc < 2) {
#pragma unroll
          for (int mt = 0; mt < 4; mt++)
            a[mt] = *(const short8*)(x_stage + (mt * 2 + kc) * 520 + loff);
        } else {
#pragma unroll
          for (int mt = 0; mt < 4; mt++)
            a[mt] = *(const short8*)(h_stage + (mt * 8 + (kc - 2)) * 520 + loff);
        }
      }
#pragma unroll
      for (int jj = 0; jj < 4; jj++) {
        const int g = half * 2 + (jj >> 1), nt2 = jj & 1;
#pragma unroll
        for (int mt = 0; mt < 4; mt++)
          acc[g][mt][nt2] = mfma16(a[mt], bb[cur][jj], acc[g][mt][nt2]);
      }
    }

    __syncthreads();  // all h_stage / x_stage reads complete

    // ---- Phase A: LSTM cell; write bf16 A-frags directly into h_stage ----
#pragma unroll
    for (int mt = 0; mt < 4; mt++) {
      float sh[4], sh2[4], sA[4], sB[4];
#pragma unroll
      for (int r = 0; r < 4; r++) {
        sh[r] = 0.f; sh2[r] = 0.f; sA[r] = 0.f; sB[r] = 0.f;
      }
#pragma unroll
      for (int nt2 = 0; nt2 < 2; nt2++)
#pragma unroll
        for (int r = 0; r < 4; r++) {
          float iv = sigm(acc[0][mt][nt2][r]);
          float fv = sigm(acc[1][mt][nt2][r]);
          float gv = tanh_(acc[2][mt][nt2][r]);
          float ov = sigm(acc[3][mt][nt2][r]);
          float cc = fv * c_r[mt][nt2][r] + iv * gv;
          c_r[mt][nt2][r] = cc;
          float hv = ov * tanh_(cc);
          // A-frag dst: chunk=(mt*8+w), slot=(q*4+r)+16*(nt2*2+(i>>3)), j=i&7
          h_stage[(mt * 8 + w) * 520 +
                  ((q * 4 + r) + 16 * (nt2 * 2 + (i >> 3))) * 8 + (i & 7)] =
              f2bf(hv);
          sh[r] += hv;
          sh2[r] += hv * hv;
          sA[r] += hv * Pp[nt2][0];
          sB[r] += hv * Pp[nt2][1];
        }
      // reduce across the 16 i-lanes
#pragma unroll
      for (int mask = 1; mask <= 8; mask <<= 1) {
#pragma unroll
        for (int r = 0; r < 4; r++) {
          sh[r] += __shfl_xor(sh[r], mask, 64);
          sh2[r] += __shfl_xor(sh2[r], mask, 64);
          sA[r] += __shfl_xor(sA[r], mask, 64);
          sB[r] += __shfl_xor(sB[r], mask, 64);
        }
      }
      if (i == 0) {
#pragma unroll
        for (int r = 0; r < 4; r++) {
          int pp = mt * 16 + q * 4 + r;
          partials[pp * 33 + w * 4 + 0] = sh[r];
          partials[pp * 33 + w * 4 + 1] = sh2[r];
          partials[pp * 33 + w * 4 + 2] = sA[r];
          partials[pp * 33 + w * 4 + 3] = sB[r];
        }
      }
    }
    __syncthreads();

    // ---- Phase B: LN2 + pos head + output + LN1 (64 threads) ----
    if (tid < 64) {
      int p = tid;
      float S = 0.f, S2 = 0.f, D0 = 0.f, D1 = 0.f;
#pragma unroll
      for (int ww = 0; ww < 8; ww++) {
        S += partials[p * 33 + ww * 4 + 0];
        S2 += partials[p * 33 + ww * 4 + 1];
        D0 += partials[p * 33 + ww * 4 + 2];
        D1 += partials[p * 33 + ww * 4 + 3];
      }
      float mu = S * (1.0f / 256.0f);
      float var = S2 * (1.0f / 256.0f) - mu * mu;
      float rsig = rsqrtf(var + 1e-5f);
      float dot0 = rsig * (D0 - mu * SP0) + K0;
      float dot1 = rsig * (D1 - mu * SP1) + K1;
      float rel0 = sigm(dot0 + pb0);
      float rel1 = sigm(dot1 + pb1);
      *(float2*)(out + (size_t)st * 16384 + (P0 + p) * 2) =
          make_float2(rel0, rel1);
      float d = 0.5f * (rel0 - rel1);
      float rs = rsqrtf(d * d + 1e-5f);
      n01[p][0] = d * rs * g10 + b10;
      n01[p][1] = -d * rs * g11 + b11;
    }
    __syncthreads();

    // ---- Phase C: next x_stage = embed(n01) ----
    {
      float n0 = n01[pc][0], n1 = n01[pc][1];
      short8 sv;
#pragma unroll
      for (int j = 0; j < 8; j++) {
        int k = s3 * 8 + j;
        float2 ew = ((const float2*)embW)[k];
        float e = n0 * ew.x + n1 * ew.y + embB[k];
        e = e > 0.f ? e : 0.01f * e;
        sv[j] = (short)f2bf(e);
      }
      *(short8*)(x_stage + ((pc >> 4) * 2 + (s3 >> 2)) * 520 +
                 ((pc & 15) + 16 * (s3 & 3)) * 8) = sv;
    }
    __syncthreads();
  }
}

extern "C" void kernel_launch(void* const* d_in, const int* in_sizes, int n_in,
                              void* d_out, int out_size, void* d_ws,
                              size_t ws_size, hipStream_t stream) {
  (void)in_sizes; (void)n_in; (void)out_size; (void)ws_size;
  const float* lpr  = (const float*)d_in[1];
  const float* h0   = (const float*)d_in[2];
  const float* c0   = (const float*)d_in[3];
  const float* Wih  = (const float*)d_in[4];
  const float* Whh  = (const float*)d_in[5];
  const float* b_ih = (const float*)d_in[6];
  const float* b_hh = (const float*)d_in[7];
  const float* embW = (const float*)d_in[8];
  const float* embB = (const float*)d_in[9];
  const float* ln1g = (const float*)d_in[10];
  const float* ln1b = (const float*)d_in[11];
  const float* posW = (const float*)d_in[12];
  const float* posB = (const float*)d_in[13];
  const float* ln2g = (const float*)d_in[14];
  const float* ln2b = (const float*)d_in[15];

  char* ws = (char*)d_ws;
  unsigned short* whh_s = (unsigned short*)(ws + WS_WHH_OFF);
  unsigned short* wih_s = (unsigned short*)(ws + WS_WIH_OFF);
  float* biasv = (float*)(ws + WS_BIAS_OFF);
  float* scal  = (float*)(ws + WS_SCAL_OFF);

  shuffle_weights<<<dim3(160), dim3(256), 0, stream>>>(Wih, Whh, whh_s, wih_s);
  prologue2<<<dim3(1), dim3(256), 0, stream>>>(b_ih, b_hh, ln2g, ln2b, posW,
                                               biasv, scal);
  decoder_main<<<dim3(128), dim3(512), 0, stream>>>(
      lpr, h0, c0, embW, embB, ln1g, ln1b, posW, posB, ln2g, whh_s, wih_s,
      biasv, scal, (float*)d_out);
}